// Round 1
// baseline (660.469 us; speedup 1.0000x reference)
//
#include <hip/hip_runtime.h>

#define NV 40962
#define NP 10242
#define KNB 7
#define C1 64
#define C2 64
#define C3 128
#define INC 8
#define OC 64
#define B 8
#define FCK (C3*NP)        // 1310976
#define NCHUNK (FCK/128)   // 10242
#define FBLK 1024

typedef __attribute__((ext_vector_type(8))) __bf16 bf16x8;
typedef __attribute__((ext_vector_type(4))) float f32x4;
typedef unsigned short ushort_t;
typedef unsigned int uint_t;

static __device__ __forceinline__ ushort_t f2bf(float f) {
    uint_t u = __float_as_uint(f);
    u = (u + 0x7FFFu + ((u >> 16) & 1u)) >> 16;
    return (ushort_t)u;
}
static __device__ __forceinline__ uint_t pack2(float a, float b) {
    return (uint_t)f2bf(a) | ((uint_t)f2bf(b) << 16);
}

// ---------------- merged prep: conv1 (blocks 0..1280) + weight swizzle (blocks 1281..1424) ----
__global__ __launch_bounds__(256) void k_pre(const float* __restrict__ x,
        const float* __restrict__ W1, const float* __restrict__ b1,
        ushort_t* __restrict__ h1bf, const float* __restrict__ W2,
        const float* __restrict__ W3, ushort_t* __restrict__ wsw) {
    __shared__ float sW[C1*INC];
    __shared__ float sb[C1];
    int tid = threadIdx.x;
    if (blockIdx.x >= 1281) {
        // weight swizzle: W2 -> fragment order, W3 -> fragment order
        int idx = (blockIdx.x - 1281)*256 + tid;
        if (idx < 28672) {
            int j = idx & 7, lane = (idx >> 3) & 63, rest = idx >> 9; // rest = kstep*4+ntile
            int ntile = rest & 3, kstep = rest >> 2;
            int quad = lane >> 4, col = lane & 15;
            int k = kstep*32 + quad*8 + j;
            int o = ntile*16 + col;
            int c = k & 63, knb = k >> 6;
            wsw[idx] = f2bf(W2[(size_t)o*(C1*KNB) + c*KNB + knb]);
        } else if (idx < 28672 + 8192) {
            int s = idx - 28672;
            int j = s & 7, lane = (s >> 3) & 63, rest = s >> 9;      // rest = kstep*8+ntile
            int ntile = rest & 7, kstep = rest >> 3;
            int quad = lane >> 4, col = lane & 15;
            int c = kstep*32 + quad*8 + j;
            int o3 = ntile*16 + col;
            wsw[idx] = f2bf(W3[(size_t)o3*C2 + c]);
        }
        return;
    }
    // conv1: h1bf[n][b][c] = bf16(relu(W1 @ x + b1))
    for (int i = tid; i < C1*INC; i += 256) sW[i] = W1[i];
    if (tid < C1) sb[tid] = b1[tid];
    __syncthreads();
    long g = (long)blockIdx.x*256 + tid;
    if (g >= (long)NV*B) return;
    int n = (int)(g >> 3);
    int b = (int)(g & 7);
    float xv[INC];
#pragma unroll
    for (int c = 0; c < INC; ++c) xv[c] = x[(size_t)b*INC*NV + (size_t)c*NV + n];
    uint4* outp = (uint4*)(h1bf + ((size_t)n*B + b)*C1);
#pragma unroll
    for (int og = 0; og < 8; ++og) {
        float h[8];
#pragma unroll
        for (int j = 0; j < 8; ++j) {
            int o = og*8 + j;
            float a = sb[o];
#pragma unroll
            for (int c = 0; c < INC; ++c) a += xv[c]*sW[o*INC + c];
            h[j] = fmaxf(a, 0.f);
        }
        uint4 u;
        u.x = pack2(h[0], h[1]); u.y = pack2(h[2], h[3]);
        u.z = pack2(h[4], h[5]); u.w = pack2(h[6], h[7]);
        outp[og] = u;
    }
}

// ---------------- conv2 MFMA: m = v*8+b (M=NV*8), K=448, N=64 ----------------
__global__ __launch_bounds__(256) void k_conv2m(const ushort_t* __restrict__ h1bf,
        const int* __restrict__ nebs, const ushort_t* __restrict__ wsw,
        const float* __restrict__ b2, ushort_t* __restrict__ h2bf) {
    int tid = threadIdx.x;
    int wave = tid >> 6, lane = tid & 63;
    int quad = lane >> 4, col = lane & 15;
    int bsub = col & 7;
    int mblock = blockIdx.x * 128;
    int mbase[2];
    int rowt[2][KNB];
    f32x4 acc[2][4];
#pragma unroll
    for (int t = 0; t < 2; ++t) {
        mbase[t] = mblock + wave*32 + t*16;
        int v = (mbase[t] + col) >> 3;
        int vc = v < NV ? v : 0;
#pragma unroll
        for (int kn = 0; kn < KNB; ++kn) rowt[t][kn] = nebs[(size_t)vc*KNB + kn];
#pragma unroll
        for (int nt = 0; nt < 4; ++nt) acc[t][nt] = (f32x4){0.f, 0.f, 0.f, 0.f};
    }
    float bv[4];
#pragma unroll
    for (int nt = 0; nt < 4; ++nt) bv[nt] = b2[nt*16 + col];
    const bf16x8* W = (const bf16x8*)wsw;
#pragma unroll
    for (int ks = 0; ks < 14; ++ks) {
        int knb = ks >> 1;
        int c0 = (ks & 1)*32 + quad*8;
        bf16x8 a0 = *(const bf16x8*)(h1bf + ((size_t)rowt[0][knb]*B + bsub)*C1 + c0);
        bf16x8 a1 = *(const bf16x8*)(h1bf + ((size_t)rowt[1][knb]*B + bsub)*C1 + c0);
#pragma unroll
        for (int nt = 0; nt < 4; ++nt) {
            bf16x8 bf = W[(ks*4 + nt)*64 + lane];
            acc[0][nt] = __builtin_amdgcn_mfma_f32_16x16x32_bf16(a0, bf, acc[0][nt], 0, 0, 0);
            acc[1][nt] = __builtin_amdgcn_mfma_f32_16x16x32_bf16(a1, bf, acc[1][nt], 0, 0, 0);
        }
    }
#pragma unroll
    for (int t = 0; t < 2; ++t) {
#pragma unroll
        for (int r = 0; r < 4; ++r) {
            int m = mbase[t] + quad*4 + r;
            if ((m >> 3) < NV) {
#pragma unroll
                for (int nt = 0; nt < 4; ++nt) {
                    float val = fmaxf(acc[t][nt][r] + bv[nt], 0.f);
                    h2bf[(size_t)m*C2 + nt*16 + col] = f2bf(val);
                }
            }
        }
    }
}

// ---------------- fused pool+conv3 MFMA: h3[b][o3][v], M=NP*8, N=128, K=64 -------------
// pooled A-fragment computed inline: max over 7 neighbor rows of h2bf (exact bf16 repack)
__global__ __launch_bounds__(256) void k_poolconv3(const ushort_t* __restrict__ h2bf,
        const int* __restrict__ nebs, const ushort_t* __restrict__ wsw3,
        const float* __restrict__ b3, float* __restrict__ h3) {
    int tid = threadIdx.x;
    int wave = tid >> 6, lane = tid & 63;
    int quad = lane >> 4, col = lane & 15;
    int m0 = blockIdx.x*64 + wave*16;
    int m = m0 + col;
    int mc = ((m >> 3) < NP) ? m : 0;
    int v = mc >> 3, bsub = mc & 7;
    int rowt[KNB];
#pragma unroll
    for (int kn = 0; kn < KNB; ++kn) rowt[kn] = nebs[(size_t)v*KNB + kn];
    f32x4 acc[8];
#pragma unroll
    for (int nt = 0; nt < 8; ++nt) acc[nt] = (f32x4){0.f, 0.f, 0.f, 0.f};
    float bv[8];
#pragma unroll
    for (int nt = 0; nt < 8; ++nt) bv[nt] = b3[nt*16 + col];
    const bf16x8* W = (const bf16x8*)wsw3;
#pragma unroll
    for (int ks = 0; ks < 2; ++ks) {
        float mx[8];
#pragma unroll
        for (int i = 0; i < 8; ++i) mx[i] = -1e30f;
#pragma unroll
        for (int kn = 0; kn < KNB; ++kn) {
            uint4 u = *(const uint4*)(h2bf + ((size_t)rowt[kn]*B + bsub)*C2 + ks*32 + quad*8);
            uint_t ws[4] = {u.x, u.y, u.z, u.w};
#pragma unroll
            for (int i = 0; i < 4; ++i) {
                float lo = __uint_as_float((ws[i] & 0xFFFFu) << 16);
                float hi = __uint_as_float(ws[i] & 0xFFFF0000u);
                mx[2*i]   = fmaxf(mx[2*i], lo);
                mx[2*i+1] = fmaxf(mx[2*i+1], hi);
            }
        }
        uint4 pk;   // exact: every mx equals one of the bf16 inputs, truncation is lossless
        pk.x = (__float_as_uint(mx[0]) >> 16) | (__float_as_uint(mx[1]) & 0xFFFF0000u);
        pk.y = (__float_as_uint(mx[2]) >> 16) | (__float_as_uint(mx[3]) & 0xFFFF0000u);
        pk.z = (__float_as_uint(mx[4]) >> 16) | (__float_as_uint(mx[5]) & 0xFFFF0000u);
        pk.w = (__float_as_uint(mx[6]) >> 16) | (__float_as_uint(mx[7]) & 0xFFFF0000u);
        bf16x8 a;
        __builtin_memcpy(&a, &pk, 16);
#pragma unroll
        for (int nt = 0; nt < 8; ++nt) {
            bf16x8 bf = W[(ks*8 + nt)*64 + lane];
            acc[nt] = __builtin_amdgcn_mfma_f32_16x16x32_bf16(a, bf, acc[nt], 0, 0, 0);
        }
    }
#pragma unroll
    for (int r = 0; r < 4; ++r) {
        int mm = m0 + quad*4 + r;
        int vv = mm >> 3, b = mm & 7;
        if (vv < NP) {
#pragma unroll
            for (int nt = 0; nt < 8; ++nt) {
                int o3 = nt*16 + col;
                h3[(size_t)b*FCK + (size_t)o3*NP + vv] = fmaxf(acc[nt][r] + bv[nt], 0.f);
            }
        }
    }
}

// ---------------- fc: split-K partials over chunks of 128 (float4 staging) ----------------
__global__ __launch_bounds__(256) void k_fc(const float* __restrict__ h3,
        const float* __restrict__ Wfc, float* __restrict__ partial) {
    __shared__ float sH[B][128];
    __shared__ float sW[OC][129];
    int tid = threadIdx.x;
    int o = tid & 63;
    int tb = tid >> 6;
    float acc0 = 0.f, acc1 = 0.f;
    for (int ch = blockIdx.x; ch < NCHUNK; ch += FBLK) {
        size_t i0 = (size_t)ch * 128;
        __syncthreads();
        {
            int bb = tid >> 5, i4 = tid & 31;
            float4 f = *(const float4*)(h3 + (size_t)bb*FCK + i0 + i4*4);
            sH[bb][i4*4+0] = f.x; sH[bb][i4*4+1] = f.y;
            sH[bb][i4*4+2] = f.z; sH[bb][i4*4+3] = f.w;
        }
#pragma unroll
        for (int j = 0; j < 8; ++j) {
            int idx = tid + j*256;
            int oo = idx >> 5, i4 = idx & 31;
            float4 f = *(const float4*)(Wfc + (size_t)oo*FCK + i0 + i4*4);
            sW[oo][i4*4+0] = f.x; sW[oo][i4*4+1] = f.y;
            sW[oo][i4*4+2] = f.z; sW[oo][i4*4+3] = f.w;
        }
        __syncthreads();
#pragma unroll 8
        for (int ii = 0; ii < 128; ++ii) {
            float w = sW[o][ii];
            acc0 += w * sH[2*tb][ii];
            acc1 += w * sH[2*tb+1][ii];
        }
    }
    partial[((size_t)blockIdx.x*B + 2*tb  )*OC + o] = acc0;
    partial[((size_t)blockIdx.x*B + 2*tb+1)*OC + o] = acc1;
}

// ---------------- fc reduce: 8 blocks x 256 threads, coalesced 256B reads ----------------
__global__ __launch_bounds__(256) void k_fcred(const float* __restrict__ partial,
        const float* __restrict__ bfc, float* __restrict__ out) {
    __shared__ float red[4][64];
    int b = blockIdx.x;
    int o = threadIdx.x & 63, jg = threadIdx.x >> 6;
    float s = 0.f;
    for (int j = jg; j < FBLK; j += 4) s += partial[((size_t)j*B + b)*OC + o];
    red[jg][o] = s;
    __syncthreads();
    if (jg == 0) out[b*OC + o] = red[0][o] + red[1][o] + red[2][o] + red[3][o] + bfc[o];
}

extern "C" void kernel_launch(void* const* d_in, const int* in_sizes, int n_in,
                              void* d_out, int out_size, void* d_ws, size_t ws_size,
                              hipStream_t stream) {
    const float* x    = (const float*)d_in[0];
    const int*   nebs = (const int*)d_in[1];
    const float* W1   = (const float*)d_in[2];
    const float* b1   = (const float*)d_in[3];
    const float* W2   = (const float*)d_in[4];
    const float* b2   = (const float*)d_in[5];
    const float* W3   = (const float*)d_in[6];
    const float* b3   = (const float*)d_in[7];
    const float* Wfc  = (const float*)d_in[8];
    const float* bfc  = (const float*)d_in[9];
    float* out = (float*)d_out;

    char* ws = (char*)d_ws;
    ushort_t* h1bf = (ushort_t*)(ws);                  // 41,945,088 B
    ushort_t* h2bf = (ushort_t*)(ws + 42000000);       // 41,945,088 B
    float*    h3   = (float*)(ws + 96000000);          // 41,951,232 B
    ushort_t* wsw  = (ushort_t*)(ws + 140000000);      // 73,728 B
    float*    part = (float*)(ws + 141000000);         // 2,097,152 B
    ushort_t* wsw3 = wsw + 28672;

    k_pre<<<1425, 256, 0, stream>>>(x, W1, b1, h1bf, W2, W3, wsw);
    k_conv2m<<<2561, 256, 0, stream>>>(h1bf, nebs, wsw, b2, h2bf);
    k_poolconv3<<<1281, 256, 0, stream>>>(h2bf, nebs, wsw3, b3, h3);
    k_fc<<<FBLK, 256, 0, stream>>>(h3, Wfc, part);
    k_fcred<<<B, 256, 0, stream>>>(part, bfc, out);
}